// Round 10
// baseline (408.339 us; speedup 1.0000x reference)
//
#include <hip/hip_runtime.h>
#include <hip/hip_bf16.h>

#define C2 340
#define HID 170
#define NB 4
#define HGT 256
#define WID 256
#define HW (HGT*WID)
#define BAND 128
#define ST 1040   // LDS row stride (u16), multiple of 8 for 16B-aligned b128
#define SPLIT 4   // tile-INTERLEAVED split: block sp does t = sp, sp+4, ...

typedef unsigned short u16;
typedef unsigned int u32;
typedef float f32x4 __attribute__((ext_vector_type(4)));
typedef short s16x8 __attribute__((ext_vector_type(8)));

__device__ __forceinline__ float bf2f(u16 u) {
  union { u32 i; float f; } v; v.i = ((u32)u) << 16; return v.f;
}
__device__ __forceinline__ u16 f2bf(float f) {
  union { float f; u32 i; } v; v.f = f;
  u32 x = v.i;
  return (u16)((x + 0x7fffu + ((x >> 16) & 1u)) >> 16);
}

// LDS anti-bank-conflict swizzle (measured 0 conflicts in round 9).
// Must be used for EVERY stA access. Bijective within a channel row.
__device__ __forceinline__ int sw(int ch, int px) {
  return px ^ ((((ch >> 2) ^ (px >> 7)) & 3) << 4);
}

__device__ const float COSTAB[8] = {1.f, 0.70710678118654752f, 0.f, -0.70710678118654752f,
                                    -1.f, -0.70710678118654752f, 0.f, 0.70710678118654752f};

// ------- prepass: transpose x [b][64][HW] f32 -> xt [b][pix][64] bf16 -------
__global__ __launch_bounds__(256) void k_xt(const float* __restrict__ x,
                                            u16* __restrict__ xt) {
  const int b = blockIdx.x >> 8;
  const int pix = ((blockIdx.x & 255) << 8) + threadIdx.x;
  const float* xp = x + (size_t)b * 64 * HW + pix;
  float v[64];
  #pragma unroll
  for (int c = 0; c < 64; ++c) v[c] = xp[(size_t)c * HW];
  u32 pk[32];
  #pragma unroll
  for (int i = 0; i < 32; ++i)
    pk[i] = (u32)f2bf(v[2*i]) | ((u32)f2bf(v[2*i+1]) << 16);
  uint4* op = (uint4*)(xt + ((size_t)b * 65536 + pix) * 64);
  #pragma unroll
  for (int i = 0; i < 8; ++i)
    op[i] = make_uint4(pk[4*i], pk[4*i+1], pk[4*i+2], pk[4*i+3]);
}

// ------- prepass: W_in [340][64] f32 -> bf16 A-fragments, padded to 352 rows -------
__global__ __launch_bounds__(256) void k_wfrag(const float* __restrict__ w_in,
                                               u16* __restrict__ wf) {
  for (int e = threadIdx.x; e < 22*2*64*8; e += 256) {
    const int r = e & 7;
    const int l = (e >> 3) & 63;
    const int ts = e >> 9;
    const int s = ts & 1, t = ts >> 1;
    const int m = t*16 + (l & 15);
    const int k = s*32 + ((l >> 4) << 3) + r;
    wf[e] = (m < C2) ? f2bf(w_in[m*64 + k]) : (u16)0;
  }
}

// ------- prepass: w_out [64][170] f32 -> bf16 A-fragments, K padded to 192 -------
__global__ __launch_bounds__(256) void k_wofrag(const float* __restrict__ w_out,
                                                u16* __restrict__ wof) {
  for (int e = threadIdx.x; e < 4*6*64*8; e += 256) {
    const int r = e & 7;
    const int l = (e >> 3) & 63;
    const int mk = e >> 9;
    const int kc = mk % 6, mt = mk / 6;
    const int m = mt*16 + (l & 15);
    const int k = kc*32 + ((l >> 4) << 3) + r;
    wof[e] = (k < HID) ? f2bf(w_out[m*HID + k]) : (u16)0;
  }
}

// ------- prepass: build per-channel conv matrix in MFMA B-fragment order -------
__global__ __launch_bounds__(256) void k_mfrag(const float* __restrict__ fw,
                                               u16* __restrict__ mf) {
  __shared__ float kern[64];
  const int c = blockIdx.x;
  if (threadIdx.x < 64) {
    const int a = threadIdx.x >> 3, bb = threadIdx.x & 7;
    float acc = 0.f;
    for (int u = 0; u < 8; ++u)
      for (int v = 0; v < 8; ++v) {
        const float wv = (v <= 4) ? fw[c*40 + u*5 + v]
                                  : fw[c*40 + ((8-u)&7)*5 + (8-v)];
        acc += wv * COSTAB[(u*a + v*bb) & 7];
      }
    kern[threadIdx.x] = acc * (1.f/64.f);
  }
  __syncthreads();
  #pragma unroll
  for (int q = 0; q < 16; ++q) {
    const int e = q * 256 + threadIdx.x;
    const int r = e & 7;
    const int l = (e >> 3) & 63;
    const int sb = e >> 9;
    const int s = sb & 1, nblk = sb >> 1;
    const int k = s*32 + ((l >> 4) << 3) + r;
    const int a = k >> 3, bcol = k & 7;
    const int n = nblk*16 + (l & 15);
    const int i = n >> 3, j = n & 7;
    mf[(size_t)c * 4096 + e] = f2bf(kern[(((i - a) & 7) << 3) + ((j - bcol) & 7)]);
  }
}

// ======= FUSED: project_in (MFMA) + per-channel 8x8 circular conv (MFMA) =======
// block = 8 rows x 128 cols region, m-tiles t = sp, sp+SPLIT, ... (phase-locked)
// 512 threads (8 waves); stA in-place: P2 writes, P3 overwrites, P4 drains.
__global__ __launch_bounds__(512, 4) void k_fused(const u16* __restrict__ xt,
                                                  const u16* __restrict__ wfrag,
                                                  const u16* __restrict__ mfrag,
                                                  u16* __restrict__ mid) {
  __shared__ __align__(16) u16 stA[16 * ST];      // 33,280 B
  const int sp   = blockIdx.x & (SPLIT-1);
  const int rest = blockIdx.x / SPLIT;
  const int hf = rest & 1;
  const int s  = (rest >> 1) & 31;
  const int b  = rest >> 6;
  const int row0 = s * 8, col0 = hf * 128;

  const int w = threadIdx.x >> 6;                 // wave 0..7 == region px-row
  const int lane = threadIdx.x & 63;
  const int lm = lane & 15, lh = lane >> 4;

  // xt B-fragments for this wave's px-row: 8 col-groups x 2 k-steps (in regs)
  s16x8 Bf[8][2];
  {
    const size_t pbase = ((size_t)b * 65536 + (size_t)(row0 + w) * 256 + col0) * 64;
    #pragma unroll
    for (int j = 0; j < 8; ++j) {
      const u16* p = xt + pbase + (j*16 + lm)*64 + lh*8;
      Bf[j][0] = *(const s16x8*)(p);
      Bf[j][1] = *(const s16x8*)(p + 32);
    }
  }

  for (int t = sp; t < 22; t += SPLIT) {
    const s16x8 A0 = *(const s16x8*)(wfrag + ((t*2 + 0)*64 + lane)*8);
    const s16x8 A1 = *(const s16x8*)(wfrag + ((t*2 + 1)*64 + lane)*8);
    __syncthreads();                              // B1: stA free (prev P4 done)
    // --- P2: projin MFMA, swizzled scatter [16ch x 1024px] into stA ---
    #pragma unroll
    for (int j = 0; j < 8; ++j) {
      f32x4 acc = {0.f,0.f,0.f,0.f};
      acc = __builtin_amdgcn_mfma_f32_16x16x32_bf16(A0, Bf[j][0], acc, 0,0,0);
      acc = __builtin_amdgcn_mfma_f32_16x16x32_bf16(A1, Bf[j][1], acc, 0,0,0);
      u16* sp_ = stA + (lh*4)*ST + sw(lh*4, w*128 + j*16 + lm);
      #pragma unroll
      for (int r = 0; r < 4; ++r)
        sp_[r*ST] = f2bf(acc[r]);                 // ch = lh*4 + r
    }
    __syncthreads();                              // B2
    // --- P3: pconv, 2 channels per wave, in-place in stA ---
    #pragma unroll
    for (int q = 0; q < 2; ++q) {
      const int cl = w*2 + q;
      const int ch = t*16 + cl;
      if (ch < C2) {
        const u16* mfc = mfrag + (size_t)ch * 4096;
        s16x8 Bc[4][2];
        #pragma unroll
        for (int nb = 0; nb < 4; ++nb)
          #pragma unroll
          for (int ks = 0; ks < 2; ++ks)
            Bc[nb][ks] = *(const s16x8*)(mfc + ((nb*2 + ks)*64 + lane)*8);
        const s16x8 Ap0 = *(const s16x8*)(stA + cl*ST + sw(cl, lh*128 + lm*8));
        const s16x8 Ap1 = *(const s16x8*)(stA + cl*ST + sw(cl, (4+lh)*128 + lm*8));
        u16* op = stA + cl*ST;
        #pragma unroll
        for (int nb = 0; nb < 4; ++nb) {
          f32x4 acc = {0.f,0.f,0.f,0.f};
          acc = __builtin_amdgcn_mfma_f32_16x16x32_bf16(Ap0, Bc[nb][0], acc, 0,0,0);
          acc = __builtin_amdgcn_mfma_f32_16x16x32_bf16(Ap1, Bc[nb][1], acc, 0,0,0);
          const int n = nb*16 + lm;               // output pixel within patch
          #pragma unroll
          for (int r = 0; r < 4; ++r) {           // patch = lh*4 + r
            const int px = (n >> 3)*128 + (lh*4 + r)*8 + (n & 7);
            op[sw(cl, px)] = f2bf(acc[r]);
          }
        }
      }
    }
    __syncthreads();                              // B3
    // --- P4: coalesced drain stA -> mid ---
    #pragma unroll
    for (int k = 0; k < 4; ++k) {
      const int u = k*512 + threadIdx.x;          // quarter-wave shares px-row
      const int cl = u >> 7, rem = u & 127;
      const int i = rem >> 4, sg = rem & 15;
      const int ch = t*16 + cl;
      if (ch < C2) {
        const uint4 v = *(const uint4*)(stA + cl*ST + sw(cl, i*128 + sg*8));
        u16* dst = mid + ((size_t)(b*C2 + ch)) * HW + (size_t)(row0 + i) * WID + col0 + sg*8;
        *(uint4*)dst = v;
      }
    }
  }
}

// ------- K3a: depthwise 3x3 + exact GELU gate, band-wise, coalesced -------
__global__ __launch_bounds__(256) void k_gate(const u16* __restrict__ mid,
                                              const float* __restrict__ w_dw,
                                              u16* __restrict__ gbuf, int hb) {
  __shared__ __align__(16) u16 sh[2][18][272];
  const int s  = blockIdx.x & 7;
  const int bc = blockIdx.x >> 3;
  const int c  = bc % HID, b = bc / HID;
  const int h0 = hb + s * 16;

  u32* shw = (u32*)sh;
  for (int i = threadIdx.x; i < 2*18*136; i += 256) shw[i] = 0;
  __syncthreads();
  for (int i = threadIdx.x; i < 2*18*32; i += 256) {
    const int k = i & 31;
    const int r = (i >> 5) % 18;
    const int ch2 = i / (18*32);
    const int h = h0 + r - 1;
    if (h >= 0 && h < HGT) {
      const u16* src = mid + ((size_t)(b*C2 + c + ch2*HID)) * HW + (size_t)h * WID + k*8;
      *(uint4*)&sh[ch2][r][8 + k*8] = *(const uint4*)src;
    }
  }
  __syncthreads();

  const int cc = threadIdx.x;
  const float* wd1 = w_dw + c * 9;
  const float* wd2 = w_dw + (c + HID) * 9;
  u16* gp = gbuf + (((size_t)(b*HID + c)) * BAND + (h0 - hb)) * WID + cc;

  float A[3][3], B2[3][3];
  #pragma unroll
  for (int ri = 0; ri < 2; ++ri)
    #pragma unroll
    for (int j = 0; j < 3; ++j) {
      A[ri][j]  = bf2f(sh[0][ri][7 + cc + j]);
      B2[ri][j] = bf2f(sh[1][ri][7 + cc + j]);
    }
  #pragma unroll 4
  for (int r = 0; r < 16; ++r) {
    #pragma unroll
    for (int j = 0; j < 3; ++j) {
      A[2][j]  = bf2f(sh[0][r+2][7 + cc + j]);
      B2[2][j] = bf2f(sh[1][r+2][7 + cc + j]);
    }
    float a1 = 0.f, a2 = 0.f;
    #pragma unroll
    for (int ri = 0; ri < 3; ++ri)
      #pragma unroll
      for (int j = 0; j < 3; ++j) {
        a1 += wd1[ri*3 + j] * A[ri][j];
        a2 += wd2[ri*3 + j] * B2[ri][j];
      }
    const float g = 0.5f * a1 * (1.f + erff(a1 * 0.70710678118654752f)) * a2;
    gp[(size_t)r * WID] = f2bf(g);
    #pragma unroll
    for (int j = 0; j < 3; ++j) {
      A[0][j] = A[1][j];  A[1][j] = A[2][j];
      B2[0][j] = B2[1][j]; B2[1][j] = B2[2][j];
    }
  }
}

// ------- K3b: project_out (170 -> 64) via MFMA -------
__global__ __launch_bounds__(256) void k_projout2(const u16* __restrict__ gbuf,
                                                  const u16* __restrict__ wof,
                                                  float* __restrict__ out, int hb) {
  const int b = blockIdx.x >> 7;                  // 128 blocks (rows) per batch
  const int p0 = (blockIdx.x & 127) << 8;
  const int w = threadIdx.x >> 6;
  const int lane = threadIdx.x & 63;
  const int lm = lane & 15, lh = lane >> 4;
  const size_t BW = (size_t)BAND * WID;
  const u16* gb = gbuf + (size_t)b * HID * BW + p0 + w*64 + lm;

  f32x4 acc[4][4];
  #pragma unroll
  for (int mt = 0; mt < 4; ++mt)
    #pragma unroll
    for (int ng = 0; ng < 4; ++ng)
      acc[mt][ng] = (f32x4){0.f,0.f,0.f,0.f};

  #pragma unroll
  for (int kc = 0; kc < 6; ++kc) {
    s16x8 A[4];
    #pragma unroll
    for (int mt = 0; mt < 4; ++mt)
      A[mt] = *(const s16x8*)(wof + ((mt*6 + kc)*64 + lane)*8);
    #pragma unroll
    for (int ng = 0; ng < 4; ++ng) {
      s16x8 Bf;
      #pragma unroll
      for (int r = 0; r < 8; ++r) {
        int c = kc*32 + lh*8 + r;
        if (kc == 5) c = min(c, HID - 1);          // A zero-padded for k>=170
        Bf[r] = (short)gb[(size_t)c * BW + ng*16];
      }
      #pragma unroll
      for (int mt = 0; mt < 4; ++mt)
        acc[mt][ng] = __builtin_amdgcn_mfma_f32_16x16x32_bf16(A[mt], Bf, acc[mt][ng], 0,0,0);
    }
  }
  float* ob = out + (size_t)b * 64 * HW + (size_t)hb * WID + p0 + w*64 + lm;
  #pragma unroll
  for (int mt = 0; mt < 4; ++mt)
    #pragma unroll
    for (int ng = 0; ng < 4; ++ng)
      #pragma unroll
      for (int r = 0; r < 4; ++r)
        ob[(size_t)(mt*16 + lh*4 + r) * HW + ng*16] = acc[mt][ng][r];
}

extern "C" void kernel_launch(void* const* d_in, const int* in_sizes, int n_in,
                              void* d_out, int out_size, void* d_ws, size_t ws_size,
                              hipStream_t stream) {
  const float* x     = (const float*)d_in[0];
  const float* w_in  = (const float*)d_in[1];
  const float* w_dw  = (const float*)d_in[2];
  const float* fw    = (const float*)d_in[3];
  const float* w_out = (const float*)d_in[4];
  float* out = (float*)d_out;

  char* ws = (char*)d_ws;
  u16* mid    = (u16*)ws;                                  // 178,257,920 B
  u16* gbuf   = (u16*)(ws + 178257920);                    // 44,564,480 B
  u16* xt     = (u16*)(ws + 178257920);                    // aliases gbuf (used before it)
  u16* wof    = (u16*)(ws + 178257920 + 44564480);         // 24,576 B (w_out A-frags)
  u16* mfrag  = (u16*)(ws + 178257920 + 44564480 + 43520); // 2,785,280 B
  u16* wfrag  = (u16*)(ws + 178257920 + 44564480 + 43520 + 2785280); // 45,056 B

  k_wofrag<<<1, 256, 0, stream>>>(w_out, wof);
  k_wfrag<<<1, 256, 0, stream>>>(w_in, wfrag);
  k_mfrag<<<C2, 256, 0, stream>>>(fw, mfrag);
  k_xt<<<NB*256, 256, 0, stream>>>(x, xt);
  k_fused<<<NB*64*SPLIT, 512, 0, stream>>>(xt, wfrag, mfrag, mid);
  for (int sb = 0; sb < 2; ++sb) {
    const int hb = sb * BAND;
    k_gate<<<NB*HID*8, 256, 0, stream>>>(mid, w_dw, gbuf, hb);
    k_projout2<<<NB*BAND, 256, 0, stream>>>(gbuf, wof, out, hb);   // 256 px per block
  }
}

// Round 11
// 400.321 us; speedup vs baseline: 1.0200x; 1.0200x over previous
//
#include <hip/hip_runtime.h>
#include <hip/hip_bf16.h>

#define C2 340
#define HID 170
#define NB 4
#define HGT 256
#define WID 256
#define HW (HGT*WID)
#define GST 272   // gate LDS row stride (u16); px lives at col 8..263

typedef unsigned short u16;
typedef unsigned int u32;
typedef float f32x4 __attribute__((ext_vector_type(4)));
typedef short s16x8 __attribute__((ext_vector_type(8)));

__device__ __forceinline__ float bf2f(u16 u) {
  union { u32 i; float f; } v; v.i = ((u32)u) << 16; return v.f;
}
__device__ __forceinline__ u16 f2bf(float f) {
  union { float f; u32 i; } v; v.f = f;
  u32 x = v.i;
  return (u16)((x + 0x7fffu + ((x >> 16) & 1u)) >> 16);
}

__device__ const float COSTAB[8] = {1.f, 0.70710678118654752f, 0.f, -0.70710678118654752f,
                                    -1.f, -0.70710678118654752f, 0.f, 0.70710678118654752f};

// ------- prepass: transpose x [b][64][HW] f32 -> xt [b][pix][64] bf16 -------
__global__ __launch_bounds__(256) void k_xt(const float* __restrict__ x,
                                            u16* __restrict__ xt) {
  const int b = blockIdx.x >> 8;
  const int pix = ((blockIdx.x & 255) << 8) + threadIdx.x;
  const float* xp = x + (size_t)b * 64 * HW + pix;
  float v[64];
  #pragma unroll
  for (int c = 0; c < 64; ++c) v[c] = xp[(size_t)c * HW];
  u32 pk[32];
  #pragma unroll
  for (int i = 0; i < 32; ++i)
    pk[i] = (u32)f2bf(v[2*i]) | ((u32)f2bf(v[2*i+1]) << 16);
  uint4* op = (uint4*)(xt + ((size_t)b * 65536 + pix) * 64);
  #pragma unroll
  for (int i = 0; i < 8; ++i)
    op[i] = make_uint4(pk[4*i], pk[4*i+1], pk[4*i+2], pk[4*i+3]);
}

// ------- prepass: W_in [340][64] f32 -> bf16 A-fragments, padded to 352 rows -------
__global__ __launch_bounds__(256) void k_wfrag(const float* __restrict__ w_in,
                                               u16* __restrict__ wf) {
  for (int e = threadIdx.x; e < 22*2*64*8; e += 256) {
    const int r = e & 7;
    const int l = (e >> 3) & 63;
    const int ts = e >> 9;
    const int s = ts & 1, t = ts >> 1;
    const int m = t*16 + (l & 15);
    const int k = s*32 + ((l >> 4) << 3) + r;
    wf[e] = (m < C2) ? f2bf(w_in[m*64 + k]) : (u16)0;
  }
}

// ------- prepass: w_out [64][170] f32 -> bf16 A-fragments, K padded to 192 -------
__global__ __launch_bounds__(256) void k_wofrag(const float* __restrict__ w_out,
                                                u16* __restrict__ wof) {
  for (int e = threadIdx.x; e < 4*6*64*8; e += 256) {
    const int r = e & 7;
    const int l = (e >> 3) & 63;
    const int mk = e >> 9;
    const int kc = mk % 6, mt = mk / 6;
    const int m = mt*16 + (l & 15);
    const int k = kc*32 + ((l >> 4) << 3) + r;
    wof[e] = (k < HID) ? f2bf(w_out[m*HID + k]) : (u16)0;
  }
}

// ---------------- K1: project_in (64 -> 340) via MFMA, LDS-transposed stores ----------------
__global__ __launch_bounds__(256) void k_projin2(const u16* __restrict__ xt,
                                                 const u16* __restrict__ wf,
                                                 u16* __restrict__ mid) {
  __shared__ __align__(16) u16 aw[22*2*64*8];     // 45056 B
  __shared__ __align__(16) u16 st[16][264];       // 8448 B epilogue tile
  for (int i = threadIdx.x; i < 22*2*64; i += 256)
    ((uint4*)aw)[i] = ((const uint4*)wf)[i];
  const int b = blockIdx.x >> 8;
  const int pix_blk = (blockIdx.x & 255) << 8;     // 256 px per block
  const int w = threadIdx.x >> 6;
  const int lane = threadIdx.x & 63;
  const int lm = lane & 15, lh = lane >> 4;
  const int pix0 = pix_blk + w*64;

  s16x8 Bf[4][2];                                  // 4 pixel groups x 2 ksteps
  const u16* xp = xt + ((size_t)b * 65536 + pix0) * 64;
  #pragma unroll
  for (int g = 0; g < 4; ++g) {
    const u16* p = xp + (g*16 + lm)*64 + lh*8;
    Bf[g][0] = *(const s16x8*)(p);
    Bf[g][1] = *(const s16x8*)(p + 32);
  }
  u16* mp = mid + (size_t)b * C2 * HW + pix_blk;
  const int ch_rd = threadIdx.x >> 4;              // 0..15 (row for writeout)
  const int seg = threadIdx.x & 15;                // 16 B segment
  for (int t = 0; t < 22; ++t) {
    const s16x8 A0 = *(const s16x8*)(aw + ((t*2 + 0)*64 + lane)*8);
    const s16x8 A1 = *(const s16x8*)(aw + ((t*2 + 1)*64 + lane)*8);
    f32x4 ac[4];
    #pragma unroll
    for (int g = 0; g < 4; ++g) {
      ac[g] = (f32x4){0.f,0.f,0.f,0.f};
      ac[g] = __builtin_amdgcn_mfma_f32_16x16x32_bf16(A0, Bf[g][0], ac[g], 0,0,0);
      ac[g] = __builtin_amdgcn_mfma_f32_16x16x32_bf16(A1, Bf[g][1], ac[g], 0,0,0);
    }
    __syncthreads();                               // st free (prev readers done; t=0: aw staged)
    #pragma unroll
    for (int g = 0; g < 4; ++g)
      #pragma unroll
      for (int r = 0; r < 4; ++r)
        st[lh*4 + r][w*64 + g*16 + lm] = f2bf(ac[g][r]);
    __syncthreads();
    const int ch = t*16 + ch_rd;
    if (ch < C2) {
      u16* dst = mp + (size_t)ch * HW + seg*16;
      *(uint4*)dst       = *(const uint4*)&st[ch_rd][seg*16];
      *(uint4*)(dst + 8) = *(const uint4*)&st[ch_rd][seg*16 + 8];
    }
  }
}

// ------- prepass: build per-channel conv matrix in MFMA B-fragment order -------
__global__ __launch_bounds__(256) void k_mfrag(const float* __restrict__ fw,
                                               u16* __restrict__ mf) {
  __shared__ float kern[64];
  const int c = blockIdx.x;
  if (threadIdx.x < 64) {
    const int a = threadIdx.x >> 3, bb = threadIdx.x & 7;
    float acc = 0.f;
    for (int u = 0; u < 8; ++u)
      for (int v = 0; v < 8; ++v) {
        const float wv = (v <= 4) ? fw[c*40 + u*5 + v]
                                  : fw[c*40 + ((8-u)&7)*5 + (8-v)];
        acc += wv * COSTAB[(u*a + v*bb) & 7];
      }
    kern[threadIdx.x] = acc * (1.f/64.f);
  }
  __syncthreads();
  #pragma unroll
  for (int q = 0; q < 16; ++q) {
    const int e = q * 256 + threadIdx.x;
    const int r = e & 7;
    const int l = (e >> 3) & 63;
    const int sb = e >> 9;
    const int s = sb & 1, nblk = sb >> 1;
    const int k = s*32 + ((l >> 4) << 3) + r;
    const int a = k >> 3, bcol = k & 7;
    const int n = nblk*16 + (l & 15);
    const int i = n >> 3, j = n & 7;
    mf[(size_t)c * 4096 + e] = f2bf(kern[(((i - a) & 7) << 3) + ((j - bcol) & 7)]);
  }
}

// ------- K2: per-channel 8x8 circular conv as MFMA GEMM, in place, LDS epilogue -------
__global__ __launch_bounds__(256) void k_pconv2(u16* __restrict__ mid,
                                                const u16* __restrict__ mf) {
  __shared__ __align__(16) u16 st[16][264];       // 16 rows x 256 cols region tile
  const int gid = blockIdx.x;
  const int half = gid & 1;
  const int bc = gid >> 1;
  const int c = bc % C2;
  const int lane = threadIdx.x & 63;
  const int w = threadIdx.x >> 6;
  u16* chan = mid + (size_t)bc * HW;

  s16x8 Bf[4][2];
  const u16* mfc = mf + (size_t)c * 4096;
  #pragma unroll
  for (int nb = 0; nb < 4; ++nb)
    #pragma unroll
    for (int s = 0; s < 2; ++s)
      Bf[nb][s] = *(const s16x8*)(mfc + ((nb*2 + s)*64 + lane)*8);

  const int lm = lane & 15, lh = lane >> 4;
  const int rr = threadIdx.x >> 4;                 // writeout row 0..15
  const int seg = threadIdx.x & 15;
  for (int it = 0; it < 8; ++it) {
    const int pg = half*512 + (it*4 + w)*16;       // 16-patch group base
    const int py = pg >> 5, px0 = pg & 31;
    const u16* aptr = chan + (size_t)(py*8 + lh)*WID + (px0 + lm)*8;
    const s16x8 A0 = *(const s16x8*)(aptr);
    const s16x8 A1 = *(const s16x8*)(aptr + 4*WID);
    f32x4 ac0 = {0.f,0.f,0.f,0.f}, ac1 = {0.f,0.f,0.f,0.f};
    f32x4 ac2 = {0.f,0.f,0.f,0.f}, ac3 = {0.f,0.f,0.f,0.f};
    ac0 = __builtin_amdgcn_mfma_f32_16x16x32_bf16(A0, Bf[0][0], ac0, 0,0,0);
    ac0 = __builtin_amdgcn_mfma_f32_16x16x32_bf16(A1, Bf[0][1], ac0, 0,0,0);
    ac1 = __builtin_amdgcn_mfma_f32_16x16x32_bf16(A0, Bf[1][0], ac1, 0,0,0);
    ac1 = __builtin_amdgcn_mfma_f32_16x16x32_bf16(A1, Bf[1][1], ac1, 0,0,0);
    ac2 = __builtin_amdgcn_mfma_f32_16x16x32_bf16(A0, Bf[2][0], ac2, 0,0,0);
    ac2 = __builtin_amdgcn_mfma_f32_16x16x32_bf16(A1, Bf[2][1], ac2, 0,0,0);
    ac3 = __builtin_amdgcn_mfma_f32_16x16x32_bf16(A0, Bf[3][0], ac3, 0,0,0);
    ac3 = __builtin_amdgcn_mfma_f32_16x16x32_bf16(A1, Bf[3][1], ac3, 0,0,0);
    __syncthreads();
    const int colbase = ((w & 1)*16 + lh*4)*8 + (lm & 7);
    const int rowbase = (w >> 1)*8 + (lm >> 3);    // + nblk*2
    #pragma unroll
    for (int r = 0; r < 4; ++r) {
      st[rowbase + 0][colbase + r*8] = f2bf(ac0[r]);
      st[rowbase + 2][colbase + r*8] = f2bf(ac1[r]);
      st[rowbase + 4][colbase + r*8] = f2bf(ac2[r]);
      st[rowbase + 6][colbase + r*8] = f2bf(ac3[r]);
    }
    __syncthreads();
    const int row0 = half*128 + it*16;             // region rows row0..row0+15
    u16* dst = chan + (size_t)(row0 + rr)*WID + seg*16;
    *(uint4*)dst       = *(const uint4*)&st[rr][seg*16];
    *(uint4*)(dst + 8) = *(const uint4*)&st[rr][seg*16 + 8];
  }
}

// ======= FUSED consumer: depthwise 3x3 + exact GELU gate + project_out MFMA =======
// block = one (b, row h); 512 threads; no gbuf intermediate.
__global__ __launch_bounds__(512) void k_gateout(const u16* __restrict__ mid,
                                                 const float* __restrict__ w_dw,
                                                 const u16* __restrict__ wof,
                                                 float* __restrict__ out) {
  __shared__ __align__(16) u16 gin[2][16][3][GST];  // 52,224 B; px at col 8
  __shared__ __align__(16) u16 gl[176 * GST];       // 95,744 B gate output
  const int b = blockIdx.x >> 8, h = blockIdx.x & 255;

  for (int i = threadIdx.x; i < 6*GST; i += 512) gl[170*GST + i] = 0;

  for (int ck = 0; ck < 11; ++ck) {
    __syncthreads();                     // gin free (prev chunk's readers done)
    // load 16 channel-pairs x 3 rows x 256 cols into gin (uint4-coalesced)
    for (int i = threadIdx.x; i < 2*16*3*32; i += 512) {
      const int sg = i & 31;
      const int j = i >> 5;              // 0..95
      const int r3 = j % 3;
      const int v = j / 3;               // 0..31
      const int cl = v & 15, half = v >> 4;
      const int c = ck*16 + cl;
      const int hh = h + r3 - 1;
      uint4 val = make_uint4(0,0,0,0);
      if (c < HID && hh >= 0 && hh < HGT)
        val = *(const uint4*)(mid + ((size_t)(b*C2 + half*HID + c)) * HW
                               + (size_t)hh * WID + sg*8);
      *(uint4*)&gin[half][cl][r3][8 + sg*8] = val;
    }
    if (threadIdx.x < 96) {              // zero-pad the +-1 halo cols
      const int r3 = threadIdx.x % 3;
      const int v = threadIdx.x / 3;
      const int cl = v & 15, half = v >> 4;
      gin[half][cl][r3][7]   = 0;
      gin[half][cl][r3][264] = 0;
    }
    __syncthreads();
    // gate: thread -> (channel cl, 8 px)
    const int cl = threadIdx.x >> 5;
    const int c = ck*16 + cl;
    const int px0 = (threadIdx.x & 31) * 8;
    if (c < HID) {
      const float* wd1 = w_dw + c * 9;
      const float* wd2 = w_dw + (c + HID) * 9;
      float a1[8], a2[8];
      #pragma unroll
      for (int p = 0; p < 8; ++p) { a1[p] = 0.f; a2[p] = 0.f; }
      #pragma unroll
      for (int rr = 0; rr < 3; ++rr) {
        {
          const u16* rp = &gin[0][cl][rr][8 + px0];
          const s16x8 vv = *(const s16x8*)rp;
          float col[10];
          col[0] = bf2f(rp[-1]);
          #pragma unroll
          for (int k2 = 0; k2 < 8; ++k2) col[k2+1] = bf2f((u16)vv[k2]);
          col[9] = bf2f(rp[8]);
          const float w0 = wd1[rr*3+0], w1 = wd1[rr*3+1], w2 = wd1[rr*3+2];
          #pragma unroll
          for (int p = 0; p < 8; ++p)
            a1[p] += w0*col[p] + w1*col[p+1] + w2*col[p+2];
        }
        {
          const u16* rp = &gin[1][cl][rr][8 + px0];
          const s16x8 vv = *(const s16x8*)rp;
          float col[10];
          col[0] = bf2f(rp[-1]);
          #pragma unroll
          for (int k2 = 0; k2 < 8; ++k2) col[k2+1] = bf2f((u16)vv[k2]);
          col[9] = bf2f(rp[8]);
          const float w0 = wd2[rr*3+0], w1 = wd2[rr*3+1], w2 = wd2[rr*3+2];
          #pragma unroll
          for (int p = 0; p < 8; ++p)
            a2[p] += w0*col[p] + w1*col[p+1] + w2*col[p+2];
        }
      }
      u16* gp = gl + c*GST + px0;
      #pragma unroll
      for (int p = 0; p < 8; ++p) {
        const float g = 0.5f * a1[p] * (1.f + erff(a1[p] * 0.70710678118654752f)) * a2[p];
        gp[p] = f2bf(g);
      }
    }
  }
  __syncthreads();
  // project_out: wave w handles pixel groups ng = 2w, 2w+1
  const int w = threadIdx.x >> 6;
  const int lane = threadIdx.x & 63;
  const int lm = lane & 15, lh = lane >> 4;
  f32x4 acc[4][2];
  #pragma unroll
  for (int mt = 0; mt < 4; ++mt) {
    acc[mt][0] = (f32x4){0.f,0.f,0.f,0.f};
    acc[mt][1] = (f32x4){0.f,0.f,0.f,0.f};
  }
  #pragma unroll
  for (int kc = 0; kc < 6; ++kc) {
    s16x8 A[4];
    #pragma unroll
    for (int mt = 0; mt < 4; ++mt)
      A[mt] = *(const s16x8*)(wof + ((mt*6 + kc)*64 + lane)*8);
    #pragma unroll
    for (int g2 = 0; g2 < 2; ++g2) {
      const int ng = w*2 + g2;
      s16x8 Bf;
      #pragma unroll
      for (int r = 0; r < 8; ++r) {
        const int k = kc*32 + lh*8 + r;
        const int row = (k < 176) ? k : 175;   // A is zero for k>=170; rows 170..175 zeroed
        Bf[r] = (short)gl[row*GST + ng*16 + lm];
      }
      #pragma unroll
      for (int mt = 0; mt < 4; ++mt)
        acc[mt][g2] = __builtin_amdgcn_mfma_f32_16x16x32_bf16(A[mt], Bf, acc[mt][g2], 0,0,0);
    }
  }
  float* ob = out + (size_t)b * 64 * HW + (size_t)h * WID;
  #pragma unroll
  for (int mt = 0; mt < 4; ++mt)
    #pragma unroll
    for (int g2 = 0; g2 < 2; ++g2) {
      const int ng = w*2 + g2;
      #pragma unroll
      for (int r = 0; r < 4; ++r)
        ob[(size_t)(mt*16 + lh*4 + r) * HW + ng*16 + lm] = acc[mt][g2][r];
    }
}

extern "C" void kernel_launch(void* const* d_in, const int* in_sizes, int n_in,
                              void* d_out, int out_size, void* d_ws, size_t ws_size,
                              hipStream_t stream) {
  const float* x     = (const float*)d_in[0];
  const float* w_in  = (const float*)d_in[1];
  const float* w_dw  = (const float*)d_in[2];
  const float* fw    = (const float*)d_in[3];
  const float* w_out = (const float*)d_in[4];
  float* out = (float*)d_out;

  char* ws = (char*)d_ws;
  u16* mid    = (u16*)ws;                                  // 178,257,920 B
  u16* xt     = (u16*)(ws + 178257920);                    // 33,554,432 B
  u16* wof    = (u16*)(ws + 178257920 + 44564480);         // 24,576 B
  u16* mfrag  = (u16*)(ws + 178257920 + 44564480 + 43520); // 2,785,280 B
  u16* wfrag  = (u16*)(ws + 178257920 + 44564480 + 43520 + 2785280); // 45,056 B

  k_wofrag<<<1, 256, 0, stream>>>(w_out, wof);
  k_wfrag<<<1, 256, 0, stream>>>(w_in, wfrag);
  k_mfrag<<<C2, 256, 0, stream>>>(fw, mfrag);
  k_xt<<<NB*256, 256, 0, stream>>>(x, xt);
  k_projin2<<<NB*256, 256, 0, stream>>>(xt, wfrag, mid);
  k_pconv2<<<NB*C2*2, 256, 0, stream>>>(mid, mfrag);
  k_gateout<<<NB*256, 512, 0, stream>>>(mid, w_dw, wof, out);
}

// Round 12
// 300.107 us; speedup vs baseline: 1.3606x; 1.3339x over previous
//
#include <hip/hip_runtime.h>
#include <hip/hip_bf16.h>

#define C2 340
#define HID 170
#define NB 4
#define HGT 256
#define WID 256
#define HW (HGT*WID)
#define BAND 128

typedef unsigned short u16;
typedef unsigned int u32;
typedef float f32x4 __attribute__((ext_vector_type(4)));
typedef short s16x8 __attribute__((ext_vector_type(8)));

__device__ __forceinline__ float bf2f(u16 u) {
  union { u32 i; float f; } v; v.i = ((u32)u) << 16; return v.f;
}
__device__ __forceinline__ u16 f2bf(float f) {
  union { float f; u32 i; } v; v.f = f;
  u32 x = v.i;
  return (u16)((x + 0x7fffu + ((x >> 16) & 1u)) >> 16);
}

__device__ const float COSTAB[8] = {1.f, 0.70710678118654752f, 0.f, -0.70710678118654752f,
                                    -1.f, -0.70710678118654752f, 0.f, 0.70710678118654752f};

// ------- prepass: transpose x [b][64][HW] f32 -> xt [b][pix][64] bf16 -------
__global__ __launch_bounds__(256) void k_xt(const float* __restrict__ x,
                                            u16* __restrict__ xt) {
  const int b = blockIdx.x >> 8;
  const int pix = ((blockIdx.x & 255) << 8) + threadIdx.x;
  const float* xp = x + (size_t)b * 64 * HW + pix;
  float v[64];
  #pragma unroll
  for (int c = 0; c < 64; ++c) v[c] = xp[(size_t)c * HW];
  u32 pk[32];
  #pragma unroll
  for (int i = 0; i < 32; ++i)
    pk[i] = (u32)f2bf(v[2*i]) | ((u32)f2bf(v[2*i+1]) << 16);
  uint4* op = (uint4*)(xt + ((size_t)b * 65536 + pix) * 64);
  #pragma unroll
  for (int i = 0; i < 8; ++i)
    op[i] = make_uint4(pk[4*i], pk[4*i+1], pk[4*i+2], pk[4*i+3]);
}

// ------- prepass: W_in [340][64] f32 -> bf16 A-fragments, padded to 352 rows -------
__global__ __launch_bounds__(256) void k_wfrag(const float* __restrict__ w_in,
                                               u16* __restrict__ wf) {
  for (int e = threadIdx.x; e < 22*2*64*8; e += 256) {
    const int r = e & 7;
    const int l = (e >> 3) & 63;
    const int ts = e >> 9;
    const int s = ts & 1, t = ts >> 1;
    const int m = t*16 + (l & 15);
    const int k = s*32 + ((l >> 4) << 3) + r;
    wf[e] = (m < C2) ? f2bf(w_in[m*64 + k]) : (u16)0;
  }
}

// ------- prepass: w_out [64][170] f32 -> bf16 A-fragments, K padded to 192 -------
__global__ __launch_bounds__(256) void k_wofrag(const float* __restrict__ w_out,
                                                u16* __restrict__ wof) {
  for (int e = threadIdx.x; e < 4*6*64*8; e += 256) {
    const int r = e & 7;
    const int l = (e >> 3) & 63;
    const int mk = e >> 9;
    const int kc = mk % 6, mt = mk / 6;
    const int m = mt*16 + (l & 15);
    const int k = kc*32 + ((l >> 4) << 3) + r;
    wof[e] = (k < HID) ? f2bf(w_out[m*HID + k]) : (u16)0;
  }
}

// ---------------- K1: project_in (64 -> 340) via MFMA; A-frags from global ----------------
__global__ __launch_bounds__(256) void k_projin2(const u16* __restrict__ xt,
                                                 const u16* __restrict__ wf,
                                                 u16* __restrict__ mid) {
  __shared__ __align__(16) u16 st[16][264];       // 8448 B epilogue tile only
  const int b = blockIdx.x >> 8;
  const int pix_blk = (blockIdx.x & 255) << 8;     // 256 px per block
  const int w = threadIdx.x >> 6;
  const int lane = threadIdx.x & 63;
  const int lm = lane & 15, lh = lane >> 4;
  const int pix0 = pix_blk + w*64;

  s16x8 Bf[4][2];                                  // 4 pixel groups x 2 ksteps
  const u16* xp = xt + ((size_t)b * 65536 + pix0) * 64;
  #pragma unroll
  for (int g = 0; g < 4; ++g) {
    const u16* p = xp + (g*16 + lm)*64 + lh*8;
    Bf[g][0] = *(const s16x8*)(p);
    Bf[g][1] = *(const s16x8*)(p + 32);
  }
  u16* mp = mid + (size_t)b * C2 * HW + pix_blk;
  const int ch_rd = threadIdx.x >> 4;              // 0..15 (row for writeout)
  const int seg = threadIdx.x & 15;                // 16 B segment
  for (int t = 0; t < 22; ++t) {
    const s16x8 A0 = *(const s16x8*)(wf + ((t*2 + 0)*64 + lane)*8);  // L1/L2-hot
    const s16x8 A1 = *(const s16x8*)(wf + ((t*2 + 1)*64 + lane)*8);
    f32x4 ac[4];
    #pragma unroll
    for (int g = 0; g < 4; ++g) {
      ac[g] = (f32x4){0.f,0.f,0.f,0.f};
      ac[g] = __builtin_amdgcn_mfma_f32_16x16x32_bf16(A0, Bf[g][0], ac[g], 0,0,0);
      ac[g] = __builtin_amdgcn_mfma_f32_16x16x32_bf16(A1, Bf[g][1], ac[g], 0,0,0);
    }
    __syncthreads();                               // st free (prev drain done)
    #pragma unroll
    for (int g = 0; g < 4; ++g)
      #pragma unroll
      for (int r = 0; r < 4; ++r)
        st[lh*4 + r][w*64 + g*16 + lm] = f2bf(ac[g][r]);
    __syncthreads();
    const int ch = t*16 + ch_rd;
    if (ch < C2) {
      u16* dst = mp + (size_t)ch * HW + seg*16;
      *(uint4*)dst       = *(const uint4*)&st[ch_rd][seg*16];
      *(uint4*)(dst + 8) = *(const uint4*)&st[ch_rd][seg*16 + 8];
    }
  }
}

// ------- prepass: build per-channel conv matrix in MFMA B-fragment order -------
__global__ __launch_bounds__(256) void k_mfrag(const float* __restrict__ fw,
                                               u16* __restrict__ mf) {
  __shared__ float kern[64];
  const int c = blockIdx.x;
  if (threadIdx.x < 64) {
    const int a = threadIdx.x >> 3, bb = threadIdx.x & 7;
    float acc = 0.f;
    for (int u = 0; u < 8; ++u)
      for (int v = 0; v < 8; ++v) {
        const float wv = (v <= 4) ? fw[c*40 + u*5 + v]
                                  : fw[c*40 + ((8-u)&7)*5 + (8-v)];
        acc += wv * COSTAB[(u*a + v*bb) & 7];
      }
    kern[threadIdx.x] = acc * (1.f/64.f);
  }
  __syncthreads();
  #pragma unroll
  for (int q = 0; q < 16; ++q) {
    const int e = q * 256 + threadIdx.x;
    const int r = e & 7;
    const int l = (e >> 3) & 63;
    const int sb = e >> 9;
    const int s = sb & 1, nblk = sb >> 1;
    const int k = s*32 + ((l >> 4) << 3) + r;
    const int a = k >> 3, bcol = k & 7;
    const int n = nblk*16 + (l & 15);
    const int i = n >> 3, j = n & 7;
    mf[(size_t)c * 4096 + e] = f2bf(kern[(((i - a) & 7) << 3) + ((j - bcol) & 7)]);
  }
}

// ------- K2: per-channel 8x8 circular conv as MFMA GEMM, in place, LDS epilogue -------
__global__ __launch_bounds__(256) void k_pconv2(u16* __restrict__ mid,
                                                const u16* __restrict__ mf) {
  __shared__ __align__(16) u16 st[16][264];       // 16 rows x 256 cols region tile
  const int gid = blockIdx.x;
  const int half = gid & 1;
  const int bc = gid >> 1;
  const int c = bc % C2;
  const int lane = threadIdx.x & 63;
  const int w = threadIdx.x >> 6;
  u16* chan = mid + (size_t)bc * HW;

  s16x8 Bf[4][2];
  const u16* mfc = mf + (size_t)c * 4096;
  #pragma unroll
  for (int nb = 0; nb < 4; ++nb)
    #pragma unroll
    for (int s = 0; s < 2; ++s)
      Bf[nb][s] = *(const s16x8*)(mfc + ((nb*2 + s)*64 + lane)*8);

  const int lm = lane & 15, lh = lane >> 4;
  const int rr = threadIdx.x >> 4;                 // writeout row 0..15
  const int seg = threadIdx.x & 15;
  for (int it = 0; it < 8; ++it) {
    const int pg = half*512 + (it*4 + w)*16;       // 16-patch group base
    const int py = pg >> 5, px0 = pg & 31;
    const u16* aptr = chan + (size_t)(py*8 + lh)*WID + (px0 + lm)*8;
    const s16x8 A0 = *(const s16x8*)(aptr);
    const s16x8 A1 = *(const s16x8*)(aptr + 4*WID);
    f32x4 ac0 = {0.f,0.f,0.f,0.f}, ac1 = {0.f,0.f,0.f,0.f};
    f32x4 ac2 = {0.f,0.f,0.f,0.f}, ac3 = {0.f,0.f,0.f,0.f};
    ac0 = __builtin_amdgcn_mfma_f32_16x16x32_bf16(A0, Bf[0][0], ac0, 0,0,0);
    ac0 = __builtin_amdgcn_mfma_f32_16x16x32_bf16(A1, Bf[0][1], ac0, 0,0,0);
    ac1 = __builtin_amdgcn_mfma_f32_16x16x32_bf16(A0, Bf[1][0], ac1, 0,0,0);
    ac1 = __builtin_amdgcn_mfma_f32_16x16x32_bf16(A1, Bf[1][1], ac1, 0,0,0);
    ac2 = __builtin_amdgcn_mfma_f32_16x16x32_bf16(A0, Bf[2][0], ac2, 0,0,0);
    ac2 = __builtin_amdgcn_mfma_f32_16x16x32_bf16(A1, Bf[2][1], ac2, 0,0,0);
    ac3 = __builtin_amdgcn_mfma_f32_16x16x32_bf16(A0, Bf[3][0], ac3, 0,0,0);
    ac3 = __builtin_amdgcn_mfma_f32_16x16x32_bf16(A1, Bf[3][1], ac3, 0,0,0);
    __syncthreads();
    const int colbase = ((w & 1)*16 + lh*4)*8 + (lm & 7);
    const int rowbase = (w >> 1)*8 + (lm >> 3);    // + nblk*2
    #pragma unroll
    for (int r = 0; r < 4; ++r) {
      st[rowbase + 0][colbase + r*8] = f2bf(ac0[r]);
      st[rowbase + 2][colbase + r*8] = f2bf(ac1[r]);
      st[rowbase + 4][colbase + r*8] = f2bf(ac2[r]);
      st[rowbase + 6][colbase + r*8] = f2bf(ac3[r]);
    }
    __syncthreads();
    const int row0 = half*128 + it*16;             // region rows row0..row0+15
    u16* dst = chan + (size_t)(row0 + rr)*WID + seg*16;
    *(uint4*)dst       = *(const uint4*)&st[rr][seg*16];
    *(uint4*)(dst + 8) = *(const uint4*)&st[rr][seg*16 + 8];
  }
}

// ------- K3a: depthwise 3x3 + exact GELU gate; 8-row slices, vector windows -------
// block = (b, c, 8-row slice); thread = 1 row x 8 px; float2 packs the two halves.
__global__ __launch_bounds__(256) void k_gate(const u16* __restrict__ mid,
                                              const float* __restrict__ w_dw,
                                              u16* __restrict__ gbuf, int hb) {
  __shared__ __align__(16) u16 sh[2][10][272];    // 10,880 B; data cols [8,264)
  const int s  = blockIdx.x & 15;                 // 16 slices of 8 rows per band
  const int bc = blockIdx.x >> 4;
  const int c  = bc % HID, b = bc / HID;
  const int h0 = hb + s * 8;

  for (int i = threadIdx.x; i < 2*10*34; i += 256)
    ((uint4*)sh)[i] = make_uint4(0,0,0,0);
  __syncthreads();
  for (int i = threadIdx.x; i < 640; i += 256) {
    const int sg = i & 31;
    const int r = (i >> 5) % 10;
    const int ch2 = i / 320;
    const int h = h0 + r - 1;
    if (h >= 0 && h < HGT)
      *(uint4*)&sh[ch2][r][8 + sg*8] =
        *(const uint4*)(mid + ((size_t)(b*C2 + c + ch2*HID)) * HW + (size_t)h * WID + sg*8);
  }
  __syncthreads();

  const int rg = threadIdx.x >> 5;                // output row 0..7
  const int cg = threadIdx.x & 31;
  const int px0 = cg * 8;
  const float* wd1 = w_dw + c * 9;
  const float* wd2 = w_dw + (c + HID) * 9;

  float ax[8], ay[8];
  #pragma unroll
  for (int p = 0; p < 8; ++p) { ax[p] = 0.f; ay[p] = 0.f; }
  #pragma unroll
  for (int wr = 0; wr < 3; ++wr) {
    const u16* r1 = &sh[0][rg + wr][px0];         // L/M/R aligned b128 reads
    const u16* r2 = &sh[1][rg + wr][px0];
    const s16x8 L1 = *(const s16x8*)r1, M1 = *(const s16x8*)(r1 + 8), R1 = *(const s16x8*)(r1 + 16);
    const s16x8 L2 = *(const s16x8*)r2, M2 = *(const s16x8*)(r2 + 8), R2 = *(const s16x8*)(r2 + 16);
    float cx[10], cy[10];
    cx[0] = bf2f((u16)L1[7]);  cy[0] = bf2f((u16)L2[7]);
    #pragma unroll
    for (int p = 0; p < 8; ++p) { cx[p+1] = bf2f((u16)M1[p]); cy[p+1] = bf2f((u16)M2[p]); }
    cx[9] = bf2f((u16)R1[0]);  cy[9] = bf2f((u16)R2[0]);
    const float w1a = wd1[wr*3+0], w1b = wd1[wr*3+1], w1c = wd1[wr*3+2];
    const float w2a = wd2[wr*3+0], w2b = wd2[wr*3+1], w2c = wd2[wr*3+2];
    #pragma unroll
    for (int p = 0; p < 8; ++p) {
      ax[p] += w1a*cx[p] + w1b*cx[p+1] + w1c*cx[p+2];
      ay[p] += w2a*cy[p] + w2b*cy[p+1] + w2c*cy[p+2];
    }
  }
  u32 pk[4];
  #pragma unroll
  for (int p2 = 0; p2 < 4; ++p2) {
    float g0 = 0.5f * ax[2*p2]   * (1.f + erff(ax[2*p2]   * 0.70710678118654752f)) * ay[2*p2];
    float g1 = 0.5f * ax[2*p2+1] * (1.f + erff(ax[2*p2+1] * 0.70710678118654752f)) * ay[2*p2+1];
    pk[p2] = (u32)f2bf(g0) | ((u32)f2bf(g1) << 16);
  }
  u16* gp = gbuf + (((size_t)(b*HID + c)) * BAND + (size_t)(s*8 + rg)) * WID + px0;
  *(uint4*)gp = make_uint4(pk[0], pk[1], pk[2], pk[3]);
}

// ------- K3b: project_out (170 -> 64) via MFMA -------
__global__ __launch_bounds__(256) void k_projout2(const u16* __restrict__ gbuf,
                                                  const u16* __restrict__ wof,
                                                  float* __restrict__ out, int hb) {
  const int b = blockIdx.x >> 7;                  // 128 blocks (rows) per batch
  const int p0 = (blockIdx.x & 127) << 8;
  const int w = threadIdx.x >> 6;
  const int lane = threadIdx.x & 63;
  const int lm = lane & 15, lh = lane >> 4;
  const size_t BW = (size_t)BAND * WID;
  const u16* gb = gbuf + (size_t)b * HID * BW + p0 + w*64 + lm;

  f32x4 acc[4][4];
  #pragma unroll
  for (int mt = 0; mt < 4; ++mt)
    #pragma unroll
    for (int ng = 0; ng < 4; ++ng)
      acc[mt][ng] = (f32x4){0.f,0.f,0.f,0.f};

  #pragma unroll
  for (int kc = 0; kc < 6; ++kc) {
    s16x8 A[4];
    #pragma unroll
    for (int mt = 0; mt < 4; ++mt)
      A[mt] = *(const s16x8*)(wof + ((mt*6 + kc)*64 + lane)*8);
    #pragma unroll
    for (int ng = 0; ng < 4; ++ng) {
      s16x8 Bf;
      #pragma unroll
      for (int r = 0; r < 8; ++r) {
        int c = kc*32 + lh*8 + r;
        if (kc == 5) c = min(c, HID - 1);          // A zero-padded for k>=170
        Bf[r] = (short)gb[(size_t)c * BW + ng*16];
      }
      #pragma unroll
      for (int mt = 0; mt < 4; ++mt)
        acc[mt][ng] = __builtin_amdgcn_mfma_f32_16x16x32_bf16(A[mt], Bf, acc[mt][ng], 0,0,0);
    }
  }
  float* ob = out + (size_t)b * 64 * HW + (size_t)hb * WID + p0 + w*64 + lm;
  #pragma unroll
  for (int mt = 0; mt < 4; ++mt)
    #pragma unroll
    for (int ng = 0; ng < 4; ++ng)
      #pragma unroll
      for (int r = 0; r < 4; ++r)
        ob[(size_t)(mt*16 + lh*4 + r) * HW + ng*16] = acc[mt][ng][r];
}

extern "C" void kernel_launch(void* const* d_in, const int* in_sizes, int n_in,
                              void* d_out, int out_size, void* d_ws, size_t ws_size,
                              hipStream_t stream) {
  const float* x     = (const float*)d_in[0];
  const float* w_in  = (const float*)d_in[1];
  const float* w_dw  = (const float*)d_in[2];
  const float* fw    = (const float*)d_in[3];
  const float* w_out = (const float*)d_in[4];
  float* out = (float*)d_out;

  char* ws = (char*)d_ws;
  u16* mid    = (u16*)ws;                                  // 178,257,920 B
  u16* gbuf   = (u16*)(ws + 178257920);                    // 44,564,480 B
  u16* xt     = (u16*)(ws + 178257920);                    // aliases gbuf (used before it)
  u16* wof    = (u16*)(ws + 178257920 + 44564480);         // 24,576 B (w_out A-frags)
  u16* mfrag  = (u16*)(ws + 178257920 + 44564480 + 43520); // 2,785,280 B
  u16* wfrag  = (u16*)(ws + 178257920 + 44564480 + 43520 + 2785280); // 45,056 B

  k_wofrag<<<1, 256, 0, stream>>>(w_out, wof);
  k_wfrag<<<1, 256, 0, stream>>>(w_in, wfrag);
  k_mfrag<<<C2, 256, 0, stream>>>(fw, mfrag);
  k_xt<<<NB*256, 256, 0, stream>>>(x, xt);
  k_projin2<<<NB*256, 256, 0, stream>>>(xt, wfrag, mid);
  k_pconv2<<<NB*C2*2, 256, 0, stream>>>(mid, mfrag);
  for (int sb = 0; sb < 2; ++sb) {
    const int hb = sb * BAND;
    k_gate<<<NB*HID*16, 256, 0, stream>>>(mid, w_dw, gbuf, hb);
    k_projout2<<<NB*BAND, 256, 0, stream>>>(gbuf, wof, out, hb);   // 256 px per block
  }
}

// Round 14
// 255.355 us; speedup vs baseline: 1.5991x; 1.1753x over previous
//
#include <hip/hip_runtime.h>
#include <hip/hip_bf16.h>

#define C2 340
#define HID 170
#define NB 4
#define HGT 256
#define WID 256
#define HW (HGT*WID)
#define BAND 128

typedef unsigned short u16;
typedef unsigned int u32;
typedef float f32x4 __attribute__((ext_vector_type(4)));
typedef short s16x8 __attribute__((ext_vector_type(8)));

__device__ __forceinline__ float bf2f(u16 u) {
  union { u32 i; float f; } v; v.i = ((u32)u) << 16; return v.f;
}
__device__ __forceinline__ u16 f2bf(float f) {
  union { float f; u32 i; } v; v.f = f;
  u32 x = v.i;
  return (u16)((x + 0x7fffu + ((x >> 16) & 1u)) >> 16);
}

__device__ const float COSTAB[8] = {1.f, 0.70710678118654752f, 0.f, -0.70710678118654752f,
                                    -1.f, -0.70710678118654752f, 0.f, 0.70710678118654752f};

// ------- merged weight prepass: mfrag (blocks 0..339), wfrag (340), wofrag (341) -------
__global__ __launch_bounds__(256) void k_prep(const float* __restrict__ w_in,
                                              const float* __restrict__ w_out,
                                              const float* __restrict__ fw,
                                              u16* __restrict__ wf,
                                              u16* __restrict__ wof,
                                              u16* __restrict__ mf) {
  __shared__ float kern[64];
  const int blk = blockIdx.x;
  if (blk < C2) {
    const int c = blk;
    if (threadIdx.x < 64) {
      const int a = threadIdx.x >> 3, bb = threadIdx.x & 7;
      float acc = 0.f;
      for (int u = 0; u < 8; ++u)
        for (int v = 0; v < 8; ++v) {
          const float wv = (v <= 4) ? fw[c*40 + u*5 + v]
                                    : fw[c*40 + ((8-u)&7)*5 + (8-v)];
          acc += wv * COSTAB[(u*a + v*bb) & 7];
        }
      kern[threadIdx.x] = acc * (1.f/64.f);
    }
    __syncthreads();
    #pragma unroll
    for (int q = 0; q < 16; ++q) {
      const int e = q * 256 + threadIdx.x;
      const int r = e & 7;
      const int l = (e >> 3) & 63;
      const int sb = e >> 9;
      const int s = sb & 1, nblk = sb >> 1;
      const int k = s*32 + ((l >> 4) << 3) + r;
      const int a = k >> 3, bcol = k & 7;
      const int n = nblk*16 + (l & 15);
      const int i = n >> 3, j = n & 7;
      mf[(size_t)c * 4096 + e] = f2bf(kern[(((i - a) & 7) << 3) + ((j - bcol) & 7)]);
    }
  } else if (blk == C2) {
    for (int e = threadIdx.x; e < 22*2*64*8; e += 256) {
      const int r = e & 7;
      const int l = (e >> 3) & 63;
      const int ts = e >> 9;
      const int s = ts & 1, t = ts >> 1;
      const int m = t*16 + (l & 15);
      const int k = s*32 + ((l >> 4) << 3) + r;
      wf[e] = (m < C2) ? f2bf(w_in[m*64 + k]) : (u16)0;
    }
  } else {
    for (int e = threadIdx.x; e < 4*6*64*8; e += 256) {
      const int r = e & 7;
      const int l = (e >> 3) & 63;
      const int mk = e >> 9;
      const int kc = mk % 6, mt = mk / 6;
      const int m = mt*16 + (l & 15);
      const int k = kc*32 + ((l >> 4) << 3) + r;
      wof[e] = (k < HID) ? f2bf(w_out[m*HID + k]) : (u16)0;
    }
  }
}

// ---------------- K1: project_in (64 -> 340) via MFMA; x read directly (fused transpose) ----------------
__global__ __launch_bounds__(256) void k_projin2(const float* __restrict__ x,
                                                 const u16* __restrict__ wf,
                                                 u16* __restrict__ mid) {
  __shared__ __align__(16) u16 st[16][264];       // 8448 B epilogue tile only
  const int b = blockIdx.x >> 8;
  const int pix_blk = (blockIdx.x & 255) << 8;     // 256 px per block
  const int w = threadIdx.x >> 6;
  const int lane = threadIdx.x & 63;
  const int lm = lane & 15, lh = lane >> 4;
  const int pix0 = pix_blk + w*64;

  // B-fragments built straight from x (f32, channel-major); same values as xt path.
  s16x8 Bf[4][2];                                  // 4 pixel groups x 2 ksteps
  {
    const float* xp = x + (size_t)b * 64 * HW + pix0;
    #pragma unroll
    for (int g = 0; g < 4; ++g)
      #pragma unroll
      for (int s = 0; s < 2; ++s) {
        s16x8 t;
        #pragma unroll
        for (int r = 0; r < 8; ++r) {
          const int ch = s*32 + lh*8 + r;          // k-index matches wfrag layout
          t[r] = (short)f2bf(xp[(size_t)ch * HW + g*16 + lm]);
        }
        Bf[g][s] = t;
      }
  }
  u16* mp = mid + (size_t)b * C2 * HW + pix_blk;
  const int ch_rd = threadIdx.x >> 4;              // 0..15 (row for writeout)
  const int seg = threadIdx.x & 15;                // 16 B segment
  for (int t = 0; t < 22; ++t) {
    const s16x8 A0 = *(const s16x8*)(wf + ((t*2 + 0)*64 + lane)*8);  // L1/L2-hot
    const s16x8 A1 = *(const s16x8*)(wf + ((t*2 + 1)*64 + lane)*8);
    f32x4 ac[4];
    #pragma unroll
    for (int g = 0; g < 4; ++g) {
      ac[g] = (f32x4){0.f,0.f,0.f,0.f};
      ac[g] = __builtin_amdgcn_mfma_f32_16x16x32_bf16(A0, Bf[g][0], ac[g], 0,0,0);
      ac[g] = __builtin_amdgcn_mfma_f32_16x16x32_bf16(A1, Bf[g][1], ac[g], 0,0,0);
    }
    __syncthreads();                               // st free (prev drain done)
    #pragma unroll
    for (int g = 0; g < 4; ++g)
      #pragma unroll
      for (int r = 0; r < 4; ++r)
        st[lh*4 + r][w*64 + g*16 + lm] = f2bf(ac[g][r]);
    __syncthreads();
    const int ch = t*16 + ch_rd;
    if (ch < C2) {
      u16* dst = mp + (size_t)ch * HW + seg*16;
      *(uint4*)dst       = *(const uint4*)&st[ch_rd][seg*16];
      *(uint4*)(dst + 8) = *(const uint4*)&st[ch_rd][seg*16 + 8];
    }
  }
}

// ------- K2: per-channel 8x8 circular conv as MFMA GEMM, in place, LDS epilogue -------
__global__ __launch_bounds__(256) void k_pconv2(u16* __restrict__ mid,
                                                const u16* __restrict__ mf) {
  __shared__ __align__(16) u16 st[16][264];       // 16 rows x 256 cols region tile
  const int gid = blockIdx.x;
  const int half = gid & 1;
  const int bc = gid >> 1;
  const int c = bc % C2;
  const int lane = threadIdx.x & 63;
  const int w = threadIdx.x >> 6;
  u16* chan = mid + (size_t)bc * HW;

  s16x8 Bf[4][2];
  const u16* mfc = mf + (size_t)c * 4096;
  #pragma unroll
  for (int nb = 0; nb < 4; ++nb)
    #pragma unroll
    for (int s = 0; s < 2; ++s)
      Bf[nb][s] = *(const s16x8*)(mfc + ((nb*2 + s)*64 + lane)*8);

  const int lm = lane & 15, lh = lane >> 4;
  const int rr = threadIdx.x >> 4;                 // writeout row 0..15
  const int seg = threadIdx.x & 15;
  for (int it = 0; it < 8; ++it) {
    const int pg = half*512 + (it*4 + w)*16;       // 16-patch group base
    const int py = pg >> 5, px0 = pg & 31;
    const u16* aptr = chan + (size_t)(py*8 + lh)*WID + (px0 + lm)*8;
    const s16x8 A0 = *(const s16x8*)(aptr);
    const s16x8 A1 = *(const s16x8*)(aptr + 4*WID);
    f32x4 ac0 = {0.f,0.f,0.f,0.f}, ac1 = {0.f,0.f,0.f,0.f};
    f32x4 ac2 = {0.f,0.f,0.f,0.f}, ac3 = {0.f,0.f,0.f,0.f};
    ac0 = __builtin_amdgcn_mfma_f32_16x16x32_bf16(A0, Bf[0][0], ac0, 0,0,0);
    ac0 = __builtin_amdgcn_mfma_f32_16x16x32_bf16(A1, Bf[0][1], ac0, 0,0,0);
    ac1 = __builtin_amdgcn_mfma_f32_16x16x32_bf16(A0, Bf[1][0], ac1, 0,0,0);
    ac1 = __builtin_amdgcn_mfma_f32_16x16x32_bf16(A1, Bf[1][1], ac1, 0,0,0);
    ac2 = __builtin_amdgcn_mfma_f32_16x16x32_bf16(A0, Bf[2][0], ac2, 0,0,0);
    ac2 = __builtin_amdgcn_mfma_f32_16x16x32_bf16(A1, Bf[2][1], ac2, 0,0,0);
    ac3 = __builtin_amdgcn_mfma_f32_16x16x32_bf16(A0, Bf[3][0], ac3, 0,0,0);
    ac3 = __builtin_amdgcn_mfma_f32_16x16x32_bf16(A1, Bf[3][1], ac3, 0,0,0);
    __syncthreads();
    const int colbase = ((w & 1)*16 + lh*4)*8 + (lm & 7);
    const int rowbase = (w >> 1)*8 + (lm >> 3);    // + nblk*2
    #pragma unroll
    for (int r = 0; r < 4; ++r) {
      st[rowbase + 0][colbase + r*8] = f2bf(ac0[r]);
      st[rowbase + 2][colbase + r*8] = f2bf(ac1[r]);
      st[rowbase + 4][colbase + r*8] = f2bf(ac2[r]);
      st[rowbase + 6][colbase + r*8] = f2bf(ac3[r]);
    }
    __syncthreads();
    const int row0 = half*128 + it*16;             // region rows row0..row0+15
    u16* dst = chan + (size_t)(row0 + rr)*WID + seg*16;
    *(uint4*)dst       = *(const uint4*)&st[rr][seg*16];
    *(uint4*)(dst + 8) = *(const uint4*)&st[rr][seg*16 + 8];
  }
}

// ------- K3a: depthwise 3x3 + exact GELU gate; 8-row slices, vector windows -------
__global__ __launch_bounds__(256) void k_gate(const u16* __restrict__ mid,
                                              const float* __restrict__ w_dw,
                                              u16* __restrict__ gbuf, int hb) {
  __shared__ __align__(16) u16 sh[2][10][272];    // 10,880 B; data cols [8,264)
  const int s  = blockIdx.x & 15;                 // 16 slices of 8 rows per band
  const int bc = blockIdx.x >> 4;
  const int c  = bc % HID, b = bc / HID;
  const int h0 = hb + s * 8;

  for (int i = threadIdx.x; i < 2*10*34; i += 256)
    ((uint4*)sh)[i] = make_uint4(0,0,0,0);
  __syncthreads();
  for (int i = threadIdx.x; i < 640; i += 256) {
    const int sg = i & 31;
    const int r = (i >> 5) % 10;
    const int ch2 = i / 320;
    const int h = h0 + r - 1;
    if (h >= 0 && h < HGT)
      *(uint4*)&sh[ch2][r][8 + sg*8] =
        *(const uint4*)(mid + ((size_t)(b*C2 + c + ch2*HID)) * HW + (size_t)h * WID + sg*8);
  }
  __syncthreads();

  const int rg = threadIdx.x >> 5;                // output row 0..7
  const int cg = threadIdx.x & 31;
  const int px0 = cg * 8;
  const float* wd1 = w_dw + c * 9;
  const float* wd2 = w_dw + (c + HID) * 9;

  float ax[8], ay[8];
  #pragma unroll
  for (int p = 0; p < 8; ++p) { ax[p] = 0.f; ay[p] = 0.f; }
  #pragma unroll
  for (int wr = 0; wr < 3; ++wr) {
    const u16* r1 = &sh[0][rg + wr][px0];         // L/M/R aligned b128 reads
    const u16* r2 = &sh[1][rg + wr][px0];
    const s16x8 L1 = *(const s16x8*)r1, M1 = *(const s16x8*)(r1 + 8), R1 = *(const s16x8*)(r1 + 16);
    const s16x8 L2 = *(const s16x8*)r2, M2 = *(const s16x8*)(r2 + 8), R2 = *(const s16x8*)(r2 + 16);
    float cx[10], cy[10];
    cx[0] = bf2f((u16)L1[7]);  cy[0] = bf2f((u16)L2[7]);
    #pragma unroll
    for (int p = 0; p < 8; ++p) { cx[p+1] = bf2f((u16)M1[p]); cy[p+1] = bf2f((u16)M2[p]); }
    cx[9] = bf2f((u16)R1[0]);  cy[9] = bf2f((u16)R2[0]);
    const float w1a = wd1[wr*3+0], w1b = wd1[wr*3+1], w1c = wd1[wr*3+2];
    const float w2a = wd2[wr*3+0], w2b = wd2[wr*3+1], w2c = wd2[wr*3+2];
    #pragma unroll
    for (int p = 0; p < 8; ++p) {
      ax[p] += w1a*cx[p] + w1b*cx[p+1] + w1c*cx[p+2];
      ay[p] += w2a*cy[p] + w2b*cy[p+1] + w2c*cy[p+2];
    }
  }
  u32 pk[4];
  #pragma unroll
  for (int p2 = 0; p2 < 4; ++p2) {
    float g0 = 0.5f * ax[2*p2]   * (1.f + erff(ax[2*p2]   * 0.70710678118654752f)) * ay[2*p2];
    float g1 = 0.5f * ax[2*p2+1] * (1.f + erff(ax[2*p2+1] * 0.70710678118654752f)) * ay[2*p2+1];
    pk[p2] = (u32)f2bf(g0) | ((u32)f2bf(g1) << 16);
  }
  u16* gp = gbuf + (((size_t)(b*HID + c)) * BAND + (size_t)(s*8 + rg)) * WID + px0;
  *(uint4*)gp = make_uint4(pk[0], pk[1], pk[2], pk[3]);
}

// ------- K3b: project_out (170 -> 64) via MFMA -------
__global__ __launch_bounds__(256) void k_projout2(const u16* __restrict__ gbuf,
                                                  const u16* __restrict__ wof,
                                                  float* __restrict__ out, int hb) {
  const int b = blockIdx.x >> 7;                  // 128 blocks (rows) per batch
  const int p0 = (blockIdx.x & 127) << 8;
  const int w = threadIdx.x >> 6;
  const int lane = threadIdx.x & 63;
  const int lm = lane & 15, lh = lane >> 4;
  const size_t BW = (size_t)BAND * WID;
  const u16* gb = gbuf + (size_t)b * HID * BW + p0 + w*64 + lm;

  f32x4 acc[4][4];
  #pragma unroll
  for (int mt = 0; mt < 4; ++mt)
    #pragma unroll
    for (int ng = 0; ng < 4; ++ng)
      acc[mt][ng] = (f32x4){0.f,0.f,0.f,0.f};

  #pragma unroll
  for (int kc = 0; kc < 6; ++kc) {
    s16x8 A[4];
    #pragma unroll
    for (int mt = 0; mt < 4; ++mt)
      A[mt] = *(const s16x8*)(wof + ((mt*6 + kc)*64 + lane)*8);
    #pragma unroll
    for (int ng = 0; ng < 4; ++ng) {
      s16x8 Bf;
      #pragma unroll
      for (int r = 0; r < 8; ++r) {
        int c = kc*32 + lh*8 + r;
        if (kc == 5) c = min(c, HID - 1);          // A zero-padded for k>=170
        Bf[r] = (short)gb[(size_t)c * BW + ng*16];
      }
      #pragma unroll
      for (int mt = 0; mt < 4; ++mt)
        acc[mt][ng] = __builtin_amdgcn_mfma_f32_16x16x32_bf16(A[mt], Bf, acc[mt][ng], 0,0,0);
    }
  }
  float* ob = out + (size_t)b * 64 * HW + (size_t)hb * WID + p0 + w*64 + lm;
  #pragma unroll
  for (int mt = 0; mt < 4; ++mt)
    #pragma unroll
    for (int ng = 0; ng < 4; ++ng)
      #pragma unroll
      for (int r = 0; r < 4; ++r)
        ob[(size_t)(mt*16 + lh*4 + r) * HW + ng*16] = acc[mt][ng][r];
}

extern "C" void kernel_launch(void* const* d_in, const int* in_sizes, int n_in,
                              void* d_out, int out_size, void* d_ws, size_t ws_size,
                              hipStream_t stream) {
  const float* x     = (const float*)d_in[0];
  const float* w_in  = (const float*)d_in[1];
  const float* w_dw  = (const float*)d_in[2];
  const float* fw    = (const float*)d_in[3];
  const float* w_out = (const float*)d_in[4];
  float* out = (float*)d_out;

  char* ws = (char*)d_ws;
  u16* mid    = (u16*)ws;                                  // 178,257,920 B
  u16* gbuf   = (u16*)(ws + 178257920);                    // 44,564,480 B
  u16* wof    = (u16*)(ws + 178257920 + 44564480);         // 24,576 B
  u16* mfrag  = (u16*)(ws + 178257920 + 44564480 + 43520); // 2,785,280 B
  u16* wfrag  = (u16*)(ws + 178257920 + 44564480 + 43520 + 2785280); // 45,056 B

  k_prep<<<C2 + 2, 256, 0, stream>>>(w_in, w_out, fw, wfrag, wof, mfrag);
  k_projin2<<<NB*256, 256, 0, stream>>>(x, wfrag, mid);
  k_pconv2<<<NB*C2*2, 256, 0, stream>>>(mid, mfrag);
  for (int sb = 0; sb < 2; ++sb) {
    const int hb = sb * BAND;
    k_gate<<<NB*HID*16, 256, 0, stream>>>(mid, w_dw, gbuf, hb);
    k_projout2<<<NB*BAND, 256, 0, stream>>>(gbuf, wof, out, hb);
  }
}

// Round 15
// 249.906 us; speedup vs baseline: 1.6340x; 1.0218x over previous
//
#include <hip/hip_runtime.h>
#include <hip/hip_bf16.h>

#define C2 340
#define HID 170
#define NB 4
#define HGT 256
#define WID 256
#define HW (HGT*WID)
#define BAND 128

typedef unsigned short u16;
typedef unsigned int u32;
typedef float f32x4 __attribute__((ext_vector_type(4)));
typedef short s16x8 __attribute__((ext_vector_type(8)));

__device__ __forceinline__ float bf2f(u16 u) {
  union { u32 i; float f; } v; v.i = ((u32)u) << 16; return v.f;
}
__device__ __forceinline__ u16 f2bf(float f) {
  union { float f; u32 i; } v; v.f = f;
  u32 x = v.i;
  return (u16)((x + 0x7fffu + ((x >> 16) & 1u)) >> 16);
}

__device__ const float COSTAB[8] = {1.f, 0.70710678118654752f, 0.f, -0.70710678118654752f,
                                    -1.f, -0.70710678118654752f, 0.f, 0.70710678118654752f};

// ------- merged weight prepass: mfrag (blocks 0..339), wfrag (340), wofrag (341) -------
__global__ __launch_bounds__(256) void k_prep(const float* __restrict__ w_in,
                                              const float* __restrict__ w_out,
                                              const float* __restrict__ fw,
                                              u16* __restrict__ wf,
                                              u16* __restrict__ wof,
                                              u16* __restrict__ mf) {
  __shared__ float kern[64];
  const int blk = blockIdx.x;
  if (blk < C2) {
    const int c = blk;
    if (threadIdx.x < 64) {
      const int a = threadIdx.x >> 3, bb = threadIdx.x & 7;
      float acc = 0.f;
      for (int u = 0; u < 8; ++u)
        for (int v = 0; v < 8; ++v) {
          const float wv = (v <= 4) ? fw[c*40 + u*5 + v]
                                    : fw[c*40 + ((8-u)&7)*5 + (8-v)];
          acc += wv * COSTAB[(u*a + v*bb) & 7];
        }
      kern[threadIdx.x] = acc * (1.f/64.f);
    }
    __syncthreads();
    #pragma unroll
    for (int q = 0; q < 16; ++q) {
      const int e = q * 256 + threadIdx.x;
      const int r = e & 7;
      const int l = (e >> 3) & 63;
      const int sb = e >> 9;
      const int s = sb & 1, nblk = sb >> 1;
      const int k = s*32 + ((l >> 4) << 3) + r;
      const int a = k >> 3, bcol = k & 7;
      const int n = nblk*16 + (l & 15);
      const int i = n >> 3, j = n & 7;
      mf[(size_t)c * 4096 + e] = f2bf(kern[(((i - a) & 7) << 3) + ((j - bcol) & 7)]);
    }
  } else if (blk == C2) {
    for (int e = threadIdx.x; e < 22*2*64*8; e += 256) {
      const int r = e & 7;
      const int l = (e >> 3) & 63;
      const int ts = e >> 9;
      const int s = ts & 1, t = ts >> 1;
      const int m = t*16 + (l & 15);
      const int k = s*32 + ((l >> 4) << 3) + r;
      wf[e] = (m < C2) ? f2bf(w_in[m*64 + k]) : (u16)0;
    }
  } else {
    for (int e = threadIdx.x; e < 4*6*64*8; e += 256) {
      const int r = e & 7;
      const int l = (e >> 3) & 63;
      const int mk = e >> 9;
      const int kc = mk % 6, mt = mk / 6;
      const int m = mt*16 + (l & 15);
      const int k = kc*32 + ((l >> 4) << 3) + r;
      wof[e] = (k < HID) ? f2bf(w_out[m*HID + k]) : (u16)0;
    }
  }
}

// ---------------- K1: project_in (64 -> 340) via MFMA; x read directly ----------------
__global__ __launch_bounds__(256) void k_projin2(const float* __restrict__ x,
                                                 const u16* __restrict__ wf,
                                                 u16* __restrict__ mid) {
  __shared__ __align__(16) u16 st[16][264];       // 8448 B epilogue tile only
  const int b = blockIdx.x >> 8;
  const int pix_blk = (blockIdx.x & 255) << 8;     // 256 px per block
  const int w = threadIdx.x >> 6;
  const int lane = threadIdx.x & 63;
  const int lm = lane & 15, lh = lane >> 4;
  const int pix0 = pix_blk + w*64;

  s16x8 Bf[4][2];                                  // 4 pixel groups x 2 ksteps
  {
    const float* xp = x + (size_t)b * 64 * HW + pix0;
    #pragma unroll
    for (int g = 0; g < 4; ++g)
      #pragma unroll
      for (int s = 0; s < 2; ++s) {
        s16x8 t;
        #pragma unroll
        for (int r = 0; r < 8; ++r) {
          const int ch = s*32 + lh*8 + r;
          t[r] = (short)f2bf(xp[(size_t)ch * HW + g*16 + lm]);
        }
        Bf[g][s] = t;
      }
  }
  u16* mp = mid + (size_t)b * C2 * HW + pix_blk;
  const int ch_rd = threadIdx.x >> 4;
  const int seg = threadIdx.x & 15;
  for (int t = 0; t < 22; ++t) {
    const s16x8 A0 = *(const s16x8*)(wf + ((t*2 + 0)*64 + lane)*8);
    const s16x8 A1 = *(const s16x8*)(wf + ((t*2 + 1)*64 + lane)*8);
    f32x4 ac[4];
    #pragma unroll
    for (int g = 0; g < 4; ++g) {
      ac[g] = (f32x4){0.f,0.f,0.f,0.f};
      ac[g] = __builtin_amdgcn_mfma_f32_16x16x32_bf16(A0, Bf[g][0], ac[g], 0,0,0);
      ac[g] = __builtin_amdgcn_mfma_f32_16x16x32_bf16(A1, Bf[g][1], ac[g], 0,0,0);
    }
    __syncthreads();
    #pragma unroll
    for (int g = 0; g < 4; ++g)
      #pragma unroll
      for (int r = 0; r < 4; ++r)
        st[lh*4 + r][w*64 + g*16 + lm] = f2bf(ac[g][r]);
    __syncthreads();
    const int ch = t*16 + ch_rd;
    if (ch < C2) {
      u16* dst = mp + (size_t)ch * HW + seg*16;
      *(uint4*)dst       = *(const uint4*)&st[ch_rd][seg*16];
      *(uint4*)(dst + 8) = *(const uint4*)&st[ch_rd][seg*16 + 8];
    }
  }
}

// ======= FUSED: pconv (MFMA -> LDS, pconv2's validated tile path) + dwconv3x3 + GELU =======
// block = (b, gate-channel c); 512 threads = 8 waves (4 per conv channel); 8 x 16-row tiles.
// st row lr <-> global row hb + it*16 + lr - 1 ; data cols [8,264), pads stay zero.
__global__ __launch_bounds__(512) void k_pcgate(const u16* __restrict__ mid,
                                                const u16* __restrict__ mf,
                                                const float* __restrict__ w_dw,
                                                u16* __restrict__ gbuf, int hb) {
  __shared__ __align__(16) u16 st[2][18][272];    // 19,584 B
  const int c = blockIdx.x % HID;
  const int b = blockIdx.x / HID;
  const int P0 = hb >> 3;

  const int w = threadIdx.x >> 6;
  const int lane = threadIdx.x & 63;
  const int lm = lane & 15, lh = lane >> 4;
  const int ch2 = w >> 2;                          // 0: channel c, 1: channel c+HID
  const int wl = w & 3;                            // pconv2 wave role
  const int prow_sub = wl >> 1;                    // patch-row within tile
  const int phalf = wl & 1;                        // 16-patch column half
  const int ch = c + ch2*HID;
  const int colbase = (phalf*16 + lh*4)*8 + (lm & 7) + 8;   // +8 col pad

  for (int i = threadIdx.x; i < 2*18*34; i += 512)
    ((uint4*)st)[i] = make_uint4(0,0,0,0);

  s16x8 Bc[4][2];
  const u16* mfc = mf + (size_t)ch * 4096;
  #pragma unroll
  for (int nb = 0; nb < 4; ++nb)
    #pragma unroll
    for (int ks = 0; ks < 2; ++ks)
      Bc[nb][ks] = *(const s16x8*)(mfc + ((nb*2 + ks)*64 + lane)*8);
  const u16* chan = mid + (size_t)(b*C2 + ch) * HW;
  const float* wd1 = w_dw + c * 9;
  const float* wd2 = w_dw + (c + HID) * 9;
  __syncthreads();

  for (int it = 0; it < 8; ++it) {
    const int py2 = P0 + it*2 + 2;                 // next patch-row (halo row 17)
    // --- phase A: rotate/zero halo rows ---
    if (it == 0) {
      for (int i = threadIdx.x; i < 2*34; i += 512)
        ((uint4*)&st[i/34][0][0])[i%34] = make_uint4(0,0,0,0);
    } else {
      for (int i = threadIdx.x; i < 2*34; i += 512)
        ((uint4*)&st[i/34][0][0])[i%34] = ((const uint4*)&st[i/34][16][0])[i%34];
    }
    if (py2 >= 32) {
      for (int i = threadIdx.x; i < 2*34; i += 512)
        ((uint4*)&st[i/34][17][0])[i%34] = make_uint4(0,0,0,0);
    }
    __syncthreads();
    // --- phase B: pconv MFMA -> st rows 1..16 (pconv2's exact formulas, +1/+8 offsets) ---
    {
      const int py = P0 + it*2 + prow_sub;
      const u16* aptr = chan + (size_t)(py*8 + lh)*WID + (phalf*16 + lm)*8;
      const s16x8 A0 = *(const s16x8*)(aptr);
      const s16x8 A1 = *(const s16x8*)(aptr + 4*WID);
      const int rowb = 1 + prow_sub*8 + (lm >> 3);
      #pragma unroll
      for (int nb = 0; nb < 4; ++nb) {
        f32x4 acc = {0.f,0.f,0.f,0.f};
        acc = __builtin_amdgcn_mfma_f32_16x16x32_bf16(A0, Bc[nb][0], acc, 0,0,0);
        acc = __builtin_amdgcn_mfma_f32_16x16x32_bf16(A1, Bc[nb][1], acc, 0,0,0);
        #pragma unroll
        for (int r = 0; r < 4; ++r)
          st[ch2][rowb + nb*2][colbase + r*8] = f2bf(acc[r]);
      }
    }
    if (wl < 2) {                                  // halo: first row of next patch-row
      if (py2 < 32) {
        const u16* ap = chan + (size_t)(py2*8 + lh)*WID + (phalf*16 + lm)*8;
        const s16x8 A0 = *(const s16x8*)(ap);
        const s16x8 A1 = *(const s16x8*)(ap + 4*WID);
        f32x4 acc = {0.f,0.f,0.f,0.f};
        acc = __builtin_amdgcn_mfma_f32_16x16x32_bf16(A0, Bc[0][0], acc, 0,0,0);
        acc = __builtin_amdgcn_mfma_f32_16x16x32_bf16(A1, Bc[0][1], acc, 0,0,0);
        if ((lm >> 3) == 0) {                      // patch row 0 -> st row 17
          #pragma unroll
          for (int r = 0; r < 4; ++r)
            st[ch2][17][colbase + r*8] = f2bf(acc[r]);
        }
      }
    } else if (it == 0) {                          // halo: last row of prev patch-row
      const int pym = P0 - 1;
      if (pym >= 0) {
        const u16* ap = chan + (size_t)(pym*8 + lh)*WID + (phalf*16 + lm)*8;
        const s16x8 A0 = *(const s16x8*)(ap);
        const s16x8 A1 = *(const s16x8*)(ap + 4*WID);
        f32x4 acc = {0.f,0.f,0.f,0.f};
        acc = __builtin_amdgcn_mfma_f32_16x16x32_bf16(A0, Bc[3][0], acc, 0,0,0);
        acc = __builtin_amdgcn_mfma_f32_16x16x32_bf16(A1, Bc[3][1], acc, 0,0,0);
        if ((lm >> 3) == 1) {                      // patch row 7 -> st row 0
          #pragma unroll
          for (int r = 0; r < 4; ++r)
            st[ch2][0][colbase + r*8] = f2bf(acc[r]);
        }
      }
    }
    __syncthreads();
    // --- phase C: dwconv 3x3 + GELU gate (k_gate's exact window code) ---
    {
      const int rg = threadIdx.x >> 5;             // output row 0..15
      const int px0 = (threadIdx.x & 31) * 8;
      float ax[8], ay[8];
      #pragma unroll
      for (int p = 0; p < 8; ++p) { ax[p] = 0.f; ay[p] = 0.f; }
      #pragma unroll
      for (int wr = 0; wr < 3; ++wr) {
        const u16* r1 = &st[0][rg + wr][px0];
        const u16* r2 = &st[1][rg + wr][px0];
        const s16x8 L1 = *(const s16x8*)r1, M1 = *(const s16x8*)(r1 + 8), R1 = *(const s16x8*)(r1 + 16);
        const s16x8 L2 = *(const s16x8*)r2, M2 = *(const s16x8*)(r2 + 8), R2 = *(const s16x8*)(r2 + 16);
        float cx[10], cy[10];
        cx[0] = bf2f((u16)L1[7]);  cy[0] = bf2f((u16)L2[7]);
        #pragma unroll
        for (int p = 0; p < 8; ++p) { cx[p+1] = bf2f((u16)M1[p]); cy[p+1] = bf2f((u16)M2[p]); }
        cx[9] = bf2f((u16)R1[0]);  cy[9] = bf2f((u16)R2[0]);
        const float w1a = wd1[wr*3+0], w1b = wd1[wr*3+1], w1c = wd1[wr*3+2];
        const float w2a = wd2[wr*3+0], w2b = wd2[wr*3+1], w2c = wd2[wr*3+2];
        #pragma unroll
        for (int p = 0; p < 8; ++p) {
          ax[p] += w1a*cx[p] + w1b*cx[p+1] + w1c*cx[p+2];
          ay[p] += w2a*cy[p] + w2b*cy[p+1] + w2c*cy[p+2];
        }
      }
      u32 pk[4];
      #pragma unroll
      for (int p2 = 0; p2 < 4; ++p2) {
        float g0 = 0.5f * ax[2*p2]   * (1.f + erff(ax[2*p2]   * 0.70710678118654752f)) * ay[2*p2];
        float g1 = 0.5f * ax[2*p2+1] * (1.f + erff(ax[2*p2+1] * 0.70710678118654752f)) * ay[2*p2+1];
        pk[p2] = (u32)f2bf(g0) | ((u32)f2bf(g1) << 16);
      }
      u16* gp = gbuf + (((size_t)(b*HID + c)) * BAND + (size_t)(it*16 + rg)) * WID + px0;
      *(uint4*)gp = make_uint4(pk[0], pk[1], pk[2], pk[3]);
    }
    __syncthreads();
  }
}

// ------- K3b: project_out (170 -> 64) via MFMA -------
__global__ __launch_bounds__(256) void k_projout2(const u16* __restrict__ gbuf,
                                                  const u16* __restrict__ wof,
                                                  float* __restrict__ out, int hb) {
  const int b = blockIdx.x >> 7;
  const int p0 = (blockIdx.x & 127) << 8;
  const int w = threadIdx.x >> 6;
  const int lane = threadIdx.x & 63;
  const int lm = lane & 15, lh = lane >> 4;
  const size_t BW = (size_t)BAND * WID;
  const u16* gb = gbuf + (size_t)b * HID * BW + p0 + w*64 + lm;

  f32x4 acc[4][4];
  #pragma unroll
  for (int mt = 0; mt < 4; ++mt)
    #pragma unroll
    for (int ng = 0; ng < 4; ++ng)
      acc[mt][ng] = (f32x4){0.f,0.f,0.f,0.f};

  #pragma unroll
  for (int kc = 0; kc < 6; ++kc) {
    s16x8 A[4];
    #pragma unroll
    for (int mt = 0; mt < 4; ++mt)
      A[mt] = *(const s16x8*)(wof + ((mt*6 + kc)*64 + lane)*8);
    #pragma unroll
    for (int ng = 0; ng < 4; ++ng) {
      s16x8 Bf;
      #pragma unroll
      for (int r = 0; r < 8; ++r) {
        int c = kc*32 + lh*8 + r;
        if (kc == 5) c = min(c, HID - 1);
        Bf[r] = (short)gb[(size_t)c * BW + ng*16];
      }
      #pragma unroll
      for (int mt = 0; mt < 4; ++mt)
        acc[mt][ng] = __builtin_amdgcn_mfma_f32_16x16x32_bf16(A[mt], Bf, acc[mt][ng], 0,0,0);
    }
  }
  float* ob = out + (size_t)b * 64 * HW + (size_t)hb * WID + p0 + w*64 + lm;
  #pragma unroll
  for (int mt = 0; mt < 4; ++mt)
    #pragma unroll
    for (int ng = 0; ng < 4; ++ng)
      #pragma unroll
      for (int r = 0; r < 4; ++r)
        ob[(size_t)(mt*16 + lh*4 + r) * HW + ng*16] = acc[mt][ng][r];
}

extern "C" void kernel_launch(void* const* d_in, const int* in_sizes, int n_in,
                              void* d_out, int out_size, void* d_ws, size_t ws_size,
                              hipStream_t stream) {
  const float* x     = (const float*)d_in[0];
  const float* w_in  = (const float*)d_in[1];
  const float* w_dw  = (const float*)d_in[2];
  const float* fw    = (const float*)d_in[3];
  const float* w_out = (const float*)d_in[4];
  float* out = (float*)d_out;

  char* ws = (char*)d_ws;
  u16* mid    = (u16*)ws;                                  // 178,257,920 B (pre-conv)
  u16* gbuf   = (u16*)(ws + 178257920);                    // 44,564,480 B
  u16* wof    = (u16*)(ws + 178257920 + 44564480);         // 24,576 B
  u16* mfrag  = (u16*)(ws + 178257920 + 44564480 + 43520); // 2,785,280 B
  u16* wfrag  = (u16*)(ws + 178257920 + 44564480 + 43520 + 2785280); // 45,056 B

  k_prep<<<C2 + 2, 256, 0, stream>>>(w_in, w_out, fw, wfrag, wof, mfrag);
  k_projin2<<<NB*256, 256, 0, stream>>>(x, wfrag, mid);
  for (int sb = 0; sb < 2; ++sb) {
    const int hb = sb * BAND;
    k_pcgate<<<NB*HID, 512, 0, stream>>>(mid, mfrag, w_dw, gbuf, hb);
    k_projout2<<<NB*BAND, 256, 0, stream>>>(gbuf, wof, out, hb);
  }
}